// Round 15
// baseline (454.938 us; speedup 1.0000x reference)
//
#include <hip/hip_runtime.h>
#include <hip/hip_bf16.h>
#include <stdint.h>

#define D 300
#define KP 320       // K padded to 10*32
#define JP 304       // out cols (19*16); zb row stride
#define P0_SHORTS 51200   // part0 image: 10 tiles x 10 kk x 512 shorts
#define P0_BYTES  102400
#define P1_BYTES  92160
#define LDS_BYTES 102400

typedef __hip_bfloat16 bf16;
typedef __bf16 bf16x8 __attribute__((ext_vector_type(8)));
typedef unsigned short us8 __attribute__((ext_vector_type(8)));
typedef float f32x4 __attribute__((ext_vector_type(4)));

static __device__ __forceinline__ unsigned short f2bu(float f) {
    bf16 h = __float2bfloat16(f);
    return *reinterpret_cast<unsigned short*>(&h);
}
static __device__ __forceinline__ float bulo(unsigned int u) {
    return __uint_as_float(u << 16);
}
static __device__ __forceinline__ float buhi(unsigned int u) {
    return __uint_as_float(u & 0xffff0000u);
}
static __device__ __forceinline__ void gload_lds16(const void* g, void* l) {
    __builtin_amdgcn_global_load_lds(
        (const __attribute__((address_space(1))) unsigned int*)g,
        (__attribute__((address_space(3))) unsigned int*)l, 16, 0, 0);
}

// ------- fused: in-degree count (blocks < cb) || W re-layout (blocks >= cb) -------
// W image, per-part contiguous: part0 [kk:10][tloc:10][kg:4][lrow:16][8],
//                               part1 [kk:10][tloc:9][kg:4][lrow:16][8] at +51200.
__global__ void k_count_twb(const int* __restrict__ col, int* __restrict__ deg, int e,
                            const float* __restrict__ W, unsigned short* __restrict__ wbp,
                            int cb) {
    int bid = blockIdx.x;
    if (bid < cb) {
        int i = bid * 256 + threadIdx.x;
        if (i < e) atomicAdd(&deg[col[i]], 1);
    } else {
        int idx = (bid - cb) * 256 + threadIdx.x;
        if (idx < JP * KP) {
            int local, tbase, kk, tloc;
            if (idx < P0_SHORTS) {
                local = idx; tbase = 0;
                int q = local >> 9; kk = q / 10; tloc = q - kk * 10;
            } else {
                local = idx - P0_SHORTS; tbase = 10;
                int q = local >> 9; kk = q / 9; tloc = q - kk * 9;
            }
            int i = local & 7;
            int lrow = (local >> 3) & 15;
            int kg = (local >> 7) & 3;
            int j = (tbase + tloc) * 16 + lrow;
            int k = kk * 32 + kg * 8 + i;
            wbp[idx] = (j < D && k < D) ? f2bu(W[j * D + k]) : (unsigned short)0;
        }
    }
}

// ------- exclusive scan of deg (within-block) + fused dinv = rsqrt(deg+1) -------
__global__ void k_scanA(const int* __restrict__ deg, int* __restrict__ ex,
                        float* __restrict__ dinv, int* __restrict__ bsum, int n) {
    __shared__ int sh[256];
    int tid = threadIdx.x;
    int base = blockIdx.x * 1024 + tid * 4;
    int v[4]; int s = 0;
#pragma unroll
    for (int t = 0; t < 4; t++) {
        int i = base + t;
        v[t] = (i < n) ? deg[i] : 0;
        if (i < n) dinv[i] = rsqrtf((float)(v[t] + 1));   // +1 = self loop
        s += v[t];
    }
    sh[tid] = s;
    __syncthreads();
    for (int off = 1; off < 256; off <<= 1) {
        int t = (tid >= off) ? sh[tid - off] : 0;
        __syncthreads();
        sh[tid] += t;
        __syncthreads();
    }
    int excl = sh[tid] - s;
#pragma unroll
    for (int t = 0; t < 4; t++) {
        int i = base + t;
        if (i < n) ex[i] = excl;
        excl += v[t];
    }
    if (tid == 255) bsum[blockIdx.x] = sh[255];
}

__global__ void k_scanB(const int* __restrict__ bsum, int* __restrict__ bexc, int nb) {
    __shared__ int sh[256];
    int tid = threadIdx.x;
    int s = (tid < nb) ? bsum[tid] : 0;
    sh[tid] = s;
    __syncthreads();
    for (int off = 1; off < 256; off <<= 1) {
        int t = (tid >= off) ? sh[tid - off] : 0;
        __syncthreads();
        sh[tid] += t;
        __syncthreads();
    }
    bexc[tid] = sh[tid] - s;
}

// ---- persistent zmm row loop for one col-part (W resident in LDS, no barriers) ----
template<int NTp, int TOFF>
static __device__ __forceinline__
void zmm_rows(const float* __restrict__ x, const unsigned short* Wsh,
              unsigned short* __restrict__ zb, int n, int nrt, int bid,
              int wid, int lane) {
    int lrow = lane & 15, kg = lane >> 4;
    for (int rt = bid; rt < nrt; rt += 256) {
        int r0 = rt * 64 + wid * 16;
        int arow = r0 + lrow; if (arow >= n) arow = n - 1;
        const float* xr = x + (size_t)arow * D;
        f32x4 acc[NTp];
#pragma unroll
        for (int t = 0; t < NTp; t++) acc[t] = f32x4{0.f, 0.f, 0.f, 0.f};
        // 2-deep A prefetch: pa/pb = chunk kk, qa/qb = chunk kk+1
        float4 pa = *(const float4*)(xr + kg * 8);
        float4 pb = *(const float4*)(xr + kg * 8 + 4);
        float4 qa = *(const float4*)(xr + 32 + kg * 8);
        float4 qb = *(const float4*)(xr + 32 + kg * 8 + 4);
        for (int kk = 0; kk < 10; kk++) {
            float4 ra, rb;
            if (kk < 8) {
                int c = (kk + 2) * 32 + kg * 8;
                int clo = (c <= 296) ? c : 0;   // k>=300 lanes hit zero W cols
                int chi = (c <= 292) ? c + 4 : 0;
                ra = *(const float4*)(xr + clo);
                rb = *(const float4*)(xr + chi);
            }
            us8 au;
            au[0] = f2bu(pa.x); au[1] = f2bu(pa.y); au[2] = f2bu(pa.z); au[3] = f2bu(pa.w);
            au[4] = f2bu(pb.x); au[5] = f2bu(pb.y); au[6] = f2bu(pb.z); au[7] = f2bu(pb.w);
            bf16x8 av = __builtin_bit_cast(bf16x8, au);
            const unsigned short* bbase = Wsh + kk * (NTp * 512) + lane * 8;
#pragma unroll
            for (int t = 0; t < NTp; t++) {
                bf16x8 bv = __builtin_bit_cast(bf16x8, *(const us8*)(bbase + t * 512));
                acc[t] = __builtin_amdgcn_mfma_f32_16x16x32_bf16(av, bv, acc[t], 0, 0, 0);
            }
            pa = qa; pb = qb; qa = ra; qb = rb;
        }
#pragma unroll
        for (int r = 0; r < 4; r++) {
            int g0 = r0 + kg * 4 + r;          // C/D: row=(lane>>4)*4+reg
            if (g0 < n) {
                unsigned short* zp = zb + (size_t)g0 * JP + TOFF;
#pragma unroll
                for (int t = 0; t < NTp; t++) zp[t * 16 + lrow] = f2bu(acc[t][r]);
            }
        }
    }
}

// ------ persistent fused kernel: 256 blocks x 320 threads (5 waves).
//   stage W part0 -> bar -> {waves0-3: rows part0 | wave4: CSR fill} -> bar ->
//   stage W part1 -> bar -> waves0-3: rows part1.
__global__ __launch_bounds__(320)
void k_zmm_fill(const float* __restrict__ x, const unsigned short* __restrict__ wbp,
                unsigned short* __restrict__ zb, int n,
                const int* __restrict__ ei, const float* __restrict__ dinv,
                const int* __restrict__ ex, const int* __restrict__ bexc,
                int* __restrict__ cursor, uint2* __restrict__ edges, int e) {
    extern __shared__ unsigned short Wsh[];
    int tid = threadIdx.x;
    int bid = blockIdx.x;
    int lane = tid & 63, wid = tid >> 6;
    int nrt = (n + 63) >> 6;
    const char* wb = (const char*)wbp;

    // ---- stage part 0: 102400 B = 320 threads x 20 x 16 B (exact) ----
#pragma unroll
    for (int j = 0; j < 20; j++) {
        int byte = (tid + 320 * j) * 16;
        gload_lds16(wb + byte, (char*)Wsh + byte);
    }
    __syncthreads();   // drains staging

    if (wid < 4) {
        zmm_rows<10, 0>(x, Wsh, zb, n, nrt, bid, wid, lane);
    } else {
        // ---- CSR fill (wave 4), slice of edges per block ----
        int echunk = (e + 255) >> 8;
        int lo = bid * echunk;
        int hi = lo + echunk; if (hi > e) hi = e;
        for (int i = lo + lane; i < hi; i += 64) {
            int r = ei[i];
            int c = ei[e + i];
            int p = atomicAdd(&cursor[c], 1);
            edges[ex[c] + bexc[c >> 10] + p] =
                make_uint2((unsigned int)r, __float_as_uint(dinv[r] * dinv[c]));
        }
    }
    __syncthreads();   // part0 reads + fill done

    // ---- stage part 1: 92160 B = 320 threads x 18 x 16 B (exact) ----
#pragma unroll
    for (int j = 0; j < 18; j++) {
        int byte = (tid + 320 * j) * 16;
        gload_lds16(wb + P0_BYTES + byte, (char*)Wsh + byte);
    }
    __syncthreads();   // drains staging

    if (wid < 4) {
        zmm_rows<9, 160>(x, Wsh, zb, n, nrt, bid, wid, lane);
    }
}

// ------ gather on z + fused epilogue: self-loop, bias, relu, L2-norm, fp32 out ------
// z row = 76 uint2 (304 bf16). lane covers uint2 slots {lane} + {64+lane if lane<12}.
__global__ void k_zgather(const uint2* __restrict__ zb2, const uint2* __restrict__ edges,
                          const int* __restrict__ ex, const int* __restrict__ bexc,
                          const int* __restrict__ deg, const float* __restrict__ dinv,
                          const float* __restrict__ bias, float* __restrict__ out, int n) {
    int w = (blockIdx.x * blockDim.x + threadIdx.x) >> 6;
    if (w >= n) return;
    int lane = threadIdx.x & 63;
    int s = ex[w] + bexc[w >> 10];
    int cnt = deg[w];             // in-degree (edges only)
    float dc = dinv[w];
    const bool p2 = lane < 12;    // slots 64..75
    float a0 = 0.f, a1 = 0.f, a2 = 0.f, a3 = 0.f;
    float a4 = 0.f, a5 = 0.f, a6 = 0.f, a7 = 0.f;
    const uint2 Z = make_uint2(0u, 0u);

#define GACC(ua, ub, wgt)                                                     \
    {                                                                         \
        a0 += (wgt) * bulo((ua).x); a1 += (wgt) * buhi((ua).x);               \
        a2 += (wgt) * bulo((ua).y); a3 += (wgt) * buhi((ua).y);               \
        a4 += (wgt) * bulo((ub).x); a5 += (wgt) * buhi((ub).x);               \
        a6 += (wgt) * bulo((ub).y); a7 += (wgt) * buhi((ub).y);               \
    }

    int t = 0;
    for (; t + 4 <= cnt; t += 4) {
        uint2 e0 = edges[s + t],     e1 = edges[s + t + 1];
        uint2 e2 = edges[s + t + 2], e3 = edges[s + t + 3];
        const uint2* q0 = zb2 + (size_t)e0.x * 76 + lane;
        const uint2* q1 = zb2 + (size_t)e1.x * 76 + lane;
        const uint2* q2 = zb2 + (size_t)e2.x * 76 + lane;
        const uint2* q3 = zb2 + (size_t)e3.x * 76 + lane;
        uint2 u0a = q0[0], u1a = q1[0], u2a = q2[0], u3a = q3[0];
        uint2 u0b = p2 ? q0[64] : Z;
        uint2 u1b = p2 ? q1[64] : Z;
        uint2 u2b = p2 ? q2[64] : Z;
        uint2 u3b = p2 ? q3[64] : Z;
        float w0 = __uint_as_float(e0.y), w1 = __uint_as_float(e1.y);
        float w2 = __uint_as_float(e2.y), w3 = __uint_as_float(e3.y);
        GACC(u0a, u0b, w0);
        GACC(u1a, u1b, w1);
        GACC(u2a, u2b, w2);
        GACC(u3a, u3b, w3);
    }
    for (; t < cnt; t++) {
        uint2 ed = edges[s + t];
        float wg = __uint_as_float(ed.y);
        const uint2* q = zb2 + (size_t)ed.x * 76 + lane;
        uint2 ua = q[0];
        uint2 ub = p2 ? q[64] : Z;
        GACC(ua, ub, wg);
    }
    {
        float sw = dc * dc;   // self loop
        const uint2* q = zb2 + (size_t)w * 76 + lane;
        uint2 ua = q[0];
        uint2 ub = p2 ? q[64] : Z;
        GACC(ua, ub, sw);
    }
#undef GACC

    // bias + relu
    float4 b0 = *(const float4*)(bias + 4 * lane);        // dims 4l..4l+3 (<256)
    float4 b1 = {0.f, 0.f, 0.f, 0.f};
    const bool wr2 = lane < 11;                           // dims 256..299
    if (wr2) b1 = *(const float4*)(bias + 256 + 4 * lane);
    float v0 = fmaxf(a0 + b0.x, 0.f), v1 = fmaxf(a1 + b0.y, 0.f);
    float v2 = fmaxf(a2 + b0.z, 0.f), v3 = fmaxf(a3 + b0.w, 0.f);
    float v4 = fmaxf(a4 + b1.x, 0.f), v5 = fmaxf(a5 + b1.y, 0.f);
    float v6 = fmaxf(a6 + b1.z, 0.f), v7 = fmaxf(a7 + b1.w, 0.f);
    float sq = v0 * v0 + v1 * v1 + v2 * v2 + v3 * v3
             + v4 * v4 + v5 * v5 + v6 * v6 + v7 * v7;
    sq += __shfl_xor(sq, 1);
    sq += __shfl_xor(sq, 2);
    sq += __shfl_xor(sq, 4);
    sq += __shfl_xor(sq, 8);
    sq += __shfl_xor(sq, 16);
    sq += __shfl_xor(sq, 32);
    float sc = rsqrtf(fmaxf(sq, 1e-24f));   // == 1/max(sqrt(sq),1e-12)

    float* op = out + (size_t)w * D;
    f32x4 o0 = {v0 * sc, v1 * sc, v2 * sc, v3 * sc};
    __builtin_nontemporal_store(o0, (f32x4*)(op + 4 * lane));
    if (wr2) {
        f32x4 o1 = {v4 * sc, v5 * sc, v6 * sc, v7 * sc};
        __builtin_nontemporal_store(o1, (f32x4*)(op + 256 + 4 * lane));
    }
}

// ---------------- host launch ----------------
extern "C" void kernel_launch(void* const* d_in, const int* in_sizes, int n_in,
                              void* d_out, int out_size, void* d_ws, size_t ws_size,
                              hipStream_t stream) {
    const float* x  = (const float*)d_in[0];
    const int*   ei = (const int*)d_in[1];
    const float* W  = (const float*)d_in[2];
    const float* b  = (const float*)d_in[3];
    float* out = (float*)d_out;
    int n = in_sizes[0] / D;
    int e = in_sizes[1] / 2;

    char* p = (char*)d_ws;
    unsigned short* zb = (unsigned short*)p; p += (size_t)n * JP * 2;
    int* deg = (int*)p;         p += (size_t)n * 4;
    int* cursor = (int*)p;      p += (size_t)n * 4;   // adjacent to deg for one memset
    float* dinv = (float*)p;    p += (size_t)n * 4;
    int* ex = (int*)p;          p += (size_t)n * 4;
    p = (char*)(((uintptr_t)p + 15) & ~(uintptr_t)15);
    uint2* edges = (uint2*)p;   p += (size_t)e * 8;
    int* bsum = (int*)p;        p += 256 * 4;
    int* bexc = (int*)p;        p += 256 * 4;
    p = (char*)(((uintptr_t)p + 15) & ~(uintptr_t)15);
    unsigned short* wbp = (unsigned short*)p; p += (size_t)JP * KP * 2;

    int nb = (n + 1023) / 1024;              // scanA blocks (<= 256)
    int cb = (e + 255) / 256;                // count blocks
    int tb = (JP * KP + 255) / 256;          // twb blocks

    (void)hipMemsetAsync(deg, 0, (size_t)n * 8, stream);   // deg + cursor
    k_count_twb<<<cb + tb, 256, 0, stream>>>(ei + e, deg, e, W, wbp, cb);
    k_scanA<<<nb, 256, 0, stream>>>(deg, ex, dinv, bsum, n);
    k_scanB<<<1, 256, 0, stream>>>(bsum, bexc, nb);
    (void)hipFuncSetAttribute((const void*)k_zmm_fill,
                              hipFuncAttributeMaxDynamicSharedMemorySize, LDS_BYTES);
    k_zmm_fill<<<256, 320, LDS_BYTES, stream>>>(x, wbp, zb, n,
                                                ei, dinv, ex, bexc, cursor, edges, e);
    k_zgather<<<(n + 3) / 4, 256, 0, stream>>>((const uint2*)zb, edges, ex, bexc,
                                               deg, dinv, b, out, n);
}

// Round 16
// 222.083 us; speedup vs baseline: 2.0485x; 2.0485x over previous
//
#include <hip/hip_runtime.h>
#include <hip/hip_bf16.h>
#include <stdint.h>

#define D 300
#define KP 320   // K padded to 10*32 (MFMA k-loop extent)
#define JP 304   // out-col padded to 19*16; also zb row stride
#define NT 19    // col tiles (16 wide) per wave

typedef __hip_bfloat16 bf16;
typedef __bf16 bf16x8 __attribute__((ext_vector_type(8)));
typedef unsigned short us8 __attribute__((ext_vector_type(8)));
typedef float f32x4 __attribute__((ext_vector_type(4)));

static __device__ __forceinline__ unsigned short f2bu(float f) {
    bf16 h = __float2bfloat16(f);
    return *reinterpret_cast<unsigned short*>(&h);
}
static __device__ __forceinline__ float bulo(unsigned int u) {
    return __uint_as_float(u << 16);
}
static __device__ __forceinline__ float buhi(unsigned int u) {
    return __uint_as_float(u & 0xffff0000u);
}
static __device__ __forceinline__ void gload_lds16(const void* g, void* l) {
    __builtin_amdgcn_global_load_lds(
        (const __attribute__((address_space(1))) unsigned int*)g,
        (__attribute__((address_space(3))) unsigned int*)l, 16, 0, 0);
}

// ------- fused: in-degree count (blocks < cb) || W re-layout (blocks >= cb) -------
// W LDS-image layout: [kk:10][t:19][kg:4][lrow:16][8] bf16, zero-padded.
__global__ void k_count_twb(const int* __restrict__ col, int* __restrict__ deg, int e,
                            const float* __restrict__ W, unsigned short* __restrict__ wbp,
                            int cb) {
    int bid = blockIdx.x;
    if (bid < cb) {
        int i = bid * 256 + threadIdx.x;
        if (i < e) atomicAdd(&deg[col[i]], 1);
    } else {
        int idx = (bid - cb) * 256 + threadIdx.x;
        if (idx < JP * KP) {
            int i = idx & 7;
            int lrow = (idx >> 3) & 15;
            int kg = (idx >> 7) & 3;
            int q = idx >> 9;             // kk*19 + t
            int kk = q / 19, t = q - kk * 19;
            int j = t * 16 + lrow;
            int k = kk * 32 + kg * 8 + i;
            wbp[idx] = (j < D && k < D) ? f2bu(W[j * D + k]) : (unsigned short)0;
        }
    }
}

// ------- exclusive scan of deg (within-block) + fused dinv = rsqrt(deg+1) -------
__global__ void k_scanA(const int* __restrict__ deg, int* __restrict__ ex,
                        float* __restrict__ dinv, int* __restrict__ bsum, int n) {
    __shared__ int sh[256];
    int tid = threadIdx.x;
    int base = blockIdx.x * 1024 + tid * 4;
    int v[4]; int s = 0;
#pragma unroll
    for (int t = 0; t < 4; t++) {
        int i = base + t;
        v[t] = (i < n) ? deg[i] : 0;
        if (i < n) dinv[i] = rsqrtf((float)(v[t] + 1));   // +1 = self loop
        s += v[t];
    }
    sh[tid] = s;
    __syncthreads();
    for (int off = 1; off < 256; off <<= 1) {
        int t = (tid >= off) ? sh[tid - off] : 0;
        __syncthreads();
        sh[tid] += t;
        __syncthreads();
    }
    int excl = sh[tid] - s;
#pragma unroll
    for (int t = 0; t < 4; t++) {
        int i = base + t;
        if (i < n) ex[i] = excl;
        excl += v[t];
    }
    if (tid == 255) bsum[blockIdx.x] = sh[255];
}

__global__ void k_scanB(const int* __restrict__ bsum, int* __restrict__ bexc, int nb) {
    __shared__ int sh[256];
    int tid = threadIdx.x;
    int s = (tid < nb) ? bsum[tid] : 0;
    sh[tid] = s;
    __syncthreads();
    for (int off = 1; off < 256; off <<= 1) {
        int t = (tid >= off) ? sh[tid - off] : 0;
        __syncthreads();
        sh[tid] += t;
        __syncthreads();
    }
    bexc[tid] = sh[tid] - s;
}

// ------ fused: z = x @ W^T (blocks < zblocks) || CSR fill (blocks >= zblocks) ------
// zmm: W SINGLE-buffered LDS (conflict-free layout, coalesced gload_lds,
//      2 barriers/k-step; 19456 B -> 8 blocks/CU for cross-block overlap);
//      A per-lane fp32 -> bf16, 1-step reg prefetch; block = 4 waves x 16 rows.
// fill: edge slot = ex[c] + bexc[c>>10] + atomic cursor; CACHED stores (L2-resident
//       for the consumer zgather -- NT stores regressed zgather by 5 us, r14).
__global__ __launch_bounds__(256)
void k_zmm_fill(const float* __restrict__ x, const unsigned short* __restrict__ wbp,
                unsigned short* __restrict__ zb, int n, int zblocks,
                const int* __restrict__ ei, const float* __restrict__ dinv,
                const int* __restrict__ ex, const int* __restrict__ bexc,
                int* __restrict__ cursor, uint2* __restrict__ edges, int e) {
    __shared__ unsigned short Wsh[JP * 32];   // 19456 B, single buffer
    if (blockIdx.x >= zblocks) {
        // ---------------- CSR fill path ----------------
        int i = (int)(blockIdx.x - zblocks) * 256 + threadIdx.x;
        if (i < e) {
            int r = ei[i];          // source
            int c = ei[e + i];      // destination
            int p = atomicAdd(&cursor[c], 1);
            edges[ex[c] + bexc[c >> 10] + p] =
                make_uint2((unsigned int)r, __float_as_uint(dinv[r] * dinv[c]));
        }
        return;
    }
    // ---------------- zmm path ----------------
    int tid = threadIdx.x;
    int lane = tid & 63, wid = tid >> 6;
    int r0 = blockIdx.x * 64 + wid * 16;
    int lrow = lane & 15, kg = lane >> 4;

    int soff[5];
#pragma unroll
    for (int j = 0; j < 5; j++) {
        int i = wid + 4 * j;
        soff[j] = (i < 19) ? (i * 1024 + lane * 16) : -1;
    }
    const char* wb = (const char*)wbp;

    int arow = r0 + lrow; if (arow >= n) arow = n - 1;
    const float* xr = x + (size_t)arow * D;

    f32x4 acc[NT];
#pragma unroll
    for (int t = 0; t < NT; t++) acc[t] = f32x4{0.f, 0.f, 0.f, 0.f};

    // A(0) into regs
    float4 pa = *(const float4*)(xr + kg * 8);
    float4 pb = *(const float4*)(xr + kg * 8 + 4);

    for (int kk = 0; kk < KP / 32; kk++) {
        // stage W(kk) into the single buffer
        {
            int gof = kk * (JP * 64);           // 19456 B per chunk
#pragma unroll
            for (int j = 0; j < 5; j++)
                if (soff[j] >= 0) gload_lds16(wb + gof + soff[j], (char*)&Wsh[0] + soff[j]);
        }
        // A(kk+1) reg prefetch (issued before the barrier, lands during compute)
        float4 na, nb2;
        if (kk < KP / 32 - 1) {
            int c = (kk + 1) * 32 + kg * 8;
            int clo = (c <= 296) ? c : 0;       // k>=300 lanes multiply zero W cols
            int chi = (c <= 292) ? c + 4 : 0;
            na  = *(const float4*)(xr + clo);
            nb2 = *(const float4*)(xr + chi);
        }
        __syncthreads();   // W(kk) staged (drains vmcnt)

        us8 au;
        au[0] = f2bu(pa.x); au[1] = f2bu(pa.y); au[2] = f2bu(pa.z); au[3] = f2bu(pa.w);
        au[4] = f2bu(pb.x); au[5] = f2bu(pb.y); au[6] = f2bu(pb.z); au[7] = f2bu(pb.w);
        bf16x8 av = __builtin_bit_cast(bf16x8, au);
        const unsigned short* bbase = &Wsh[0] + lane * 8;   // + t*512 shorts
#pragma unroll
        for (int t = 0; t < NT; t++) {
            bf16x8 bv = __builtin_bit_cast(bf16x8, *(const us8*)(bbase + t * 512));
            acc[t] = __builtin_amdgcn_mfma_f32_16x16x32_bf16(av, bv, acc[t], 0, 0, 0);
        }
        __syncthreads();   // all reads of Wsh done before next stage overwrites
        pa = na; pb = nb2;
    }

#pragma unroll
    for (int r = 0; r < 4; r++) {
        int g0 = r0 + kg * 4 + r;          // C/D: row=(lane>>4)*4+reg
        if (g0 < n) {
            unsigned short* zp0 = zb + (size_t)g0 * JP;
#pragma unroll
            for (int t = 0; t < NT; t++) {
                int j = t * 16 + lrow;
                zp0[j] = f2bu(acc[t][r]);
            }
        }
    }
}

// ------ gather on z + fused epilogue: self-loop, bias, relu, L2-norm, fp32 out ------
// z row = 76 uint2 (304 bf16). lane covers uint2 slots {lane} + {64+lane if lane<12}.
__global__ void k_zgather(const uint2* __restrict__ zb2, const uint2* __restrict__ edges,
                          const int* __restrict__ ex, const int* __restrict__ bexc,
                          const int* __restrict__ deg, const float* __restrict__ dinv,
                          const float* __restrict__ bias, float* __restrict__ out, int n) {
    int w = (blockIdx.x * blockDim.x + threadIdx.x) >> 6;
    if (w >= n) return;
    int lane = threadIdx.x & 63;
    int s = ex[w] + bexc[w >> 10];
    int cnt = deg[w];             // in-degree (edges only)
    float dc = dinv[w];
    const bool p2 = lane < 12;    // slots 64..75
    float a0 = 0.f, a1 = 0.f, a2 = 0.f, a3 = 0.f;
    float a4 = 0.f, a5 = 0.f, a6 = 0.f, a7 = 0.f;
    const uint2 Z = make_uint2(0u, 0u);

#define GACC(ua, ub, wgt)                                                     \
    {                                                                         \
        a0 += (wgt) * bulo((ua).x); a1 += (wgt) * buhi((ua).x);               \
        a2 += (wgt) * bulo((ua).y); a3 += (wgt) * buhi((ua).y);               \
        a4 += (wgt) * bulo((ub).x); a5 += (wgt) * buhi((ub).x);               \
        a6 += (wgt) * bulo((ub).y); a7 += (wgt) * buhi((ub).y);               \
    }

    int t = 0;
    for (; t + 4 <= cnt; t += 4) {
        uint2 e0 = edges[s + t],     e1 = edges[s + t + 1];
        uint2 e2 = edges[s + t + 2], e3 = edges[s + t + 3];
        const uint2* q0 = zb2 + (size_t)e0.x * 76 + lane;
        const uint2* q1 = zb2 + (size_t)e1.x * 76 + lane;
        const uint2* q2 = zb2 + (size_t)e2.x * 76 + lane;
        const uint2* q3 = zb2 + (size_t)e3.x * 76 + lane;
        uint2 u0a = q0[0], u1a = q1[0], u2a = q2[0], u3a = q3[0];
        uint2 u0b = p2 ? q0[64] : Z;
        uint2 u1b = p2 ? q1[64] : Z;
        uint2 u2b = p2 ? q2[64] : Z;
        uint2 u3b = p2 ? q3[64] : Z;
        float w0 = __uint_as_float(e0.y), w1 = __uint_as_float(e1.y);
        float w2 = __uint_as_float(e2.y), w3 = __uint_as_float(e3.y);
        GACC(u0a, u0b, w0);
        GACC(u1a, u1b, w1);
        GACC(u2a, u2b, w2);
        GACC(u3a, u3b, w3);
    }
    for (; t < cnt; t++) {
        uint2 ed = edges[s + t];
        float wg = __uint_as_float(ed.y);
        const uint2* q = zb2 + (size_t)ed.x * 76 + lane;
        uint2 ua = q[0];
        uint2 ub = p2 ? q[64] : Z;
        GACC(ua, ub, wg);
    }
    {
        float sw = dc * dc;   // self loop
        const uint2* q = zb2 + (size_t)w * 76 + lane;
        uint2 ua = q[0];
        uint2 ub = p2 ? q[64] : Z;
        GACC(ua, ub, sw);
    }
#undef GACC

    // bias + relu
    float4 b0 = *(const float4*)(bias + 4 * lane);        // dims 4l..4l+3 (<256)
    float4 b1 = {0.f, 0.f, 0.f, 0.f};
    const bool wr2 = lane < 11;                           // dims 256..299
    if (wr2) b1 = *(const float4*)(bias + 256 + 4 * lane);
    float v0 = fmaxf(a0 + b0.x, 0.f), v1 = fmaxf(a1 + b0.y, 0.f);
    float v2 = fmaxf(a2 + b0.z, 0.f), v3 = fmaxf(a3 + b0.w, 0.f);
    float v4 = fmaxf(a4 + b1.x, 0.f), v5 = fmaxf(a5 + b1.y, 0.f);
    float v6 = fmaxf(a6 + b1.z, 0.f), v7 = fmaxf(a7 + b1.w, 0.f);
    float sq = v0 * v0 + v1 * v1 + v2 * v2 + v3 * v3
             + v4 * v4 + v5 * v5 + v6 * v6 + v7 * v7;
    sq += __shfl_xor(sq, 1);
    sq += __shfl_xor(sq, 2);
    sq += __shfl_xor(sq, 4);
    sq += __shfl_xor(sq, 8);
    sq += __shfl_xor(sq, 16);
    sq += __shfl_xor(sq, 32);
    float sc = rsqrtf(fmaxf(sq, 1e-24f));   // == 1/max(sqrt(sq),1e-12)

    // non-temporal out stores (out is never re-read; keeps z resident in L2)
    float* op = out + (size_t)w * D;
    f32x4 o0 = {v0 * sc, v1 * sc, v2 * sc, v3 * sc};
    __builtin_nontemporal_store(o0, (f32x4*)(op + 4 * lane));
    if (wr2) {
        f32x4 o1 = {v4 * sc, v5 * sc, v6 * sc, v7 * sc};
        __builtin_nontemporal_store(o1, (f32x4*)(op + 256 + 4 * lane));
    }
}

// ---------------- host launch ----------------
extern "C" void kernel_launch(void* const* d_in, const int* in_sizes, int n_in,
                              void* d_out, int out_size, void* d_ws, size_t ws_size,
                              hipStream_t stream) {
    const float* x  = (const float*)d_in[0];
    const int*   ei = (const int*)d_in[1];
    const float* W  = (const float*)d_in[2];
    const float* b  = (const float*)d_in[3];
    float* out = (float*)d_out;
    int n = in_sizes[0] / D;
    int e = in_sizes[1] / 2;

    char* p = (char*)d_ws;
    unsigned short* zb = (unsigned short*)p; p += (size_t)n * JP * 2;
    int* deg = (int*)p;         p += (size_t)n * 4;
    int* cursor = (int*)p;      p += (size_t)n * 4;   // adjacent to deg for one memset
    float* dinv = (float*)p;    p += (size_t)n * 4;
    int* ex = (int*)p;          p += (size_t)n * 4;
    p = (char*)(((uintptr_t)p + 15) & ~(uintptr_t)15);
    uint2* edges = (uint2*)p;   p += (size_t)e * 8;
    int* bsum = (int*)p;        p += 256 * 4;
    int* bexc = (int*)p;        p += 256 * 4;
    p = (char*)(((uintptr_t)p + 15) & ~(uintptr_t)15);
    unsigned short* wbp = (unsigned short*)p; p += (size_t)JP * KP * 2;

    int nb = (n + 1023) / 1024;              // scanA blocks (<= 256)
    int cb = (e + 255) / 256;                // count blocks
    int tb = (JP * KP + 255) / 256;          // twb blocks
    int zblocks = (n + 63) / 64;             // zmm blocks
    int fb = (e + 255) / 256;                // fill blocks

    (void)hipMemsetAsync(deg, 0, (size_t)n * 8, stream);   // deg + cursor
    k_count_twb<<<cb + tb, 256, 0, stream>>>(ei + e, deg, e, W, wbp, cb);
    k_scanA<<<nb, 256, 0, stream>>>(deg, ex, dinv, bsum, n);
    k_scanB<<<1, 256, 0, stream>>>(bsum, bexc, nb);
    k_zmm_fill<<<zblocks + fb, 256, 0, stream>>>(x, wbp, zb, n, zblocks,
                                                 ei, dinv, ex, bexc, cursor, edges, e);
    k_zgather<<<(n + 3) / 4, 256, 0, stream>>>((const uint2*)zb, edges, ex, bexc,
                                               deg, dinv, b, out, n);
}